// Round 21
// baseline (239.988 us; speedup 1.0000x reference)
//
#include <hip/hip_runtime.h>
#include <hip/hip_fp16.h>
#include <cstdint>

#define N_NODES 50000
#define B_SZ 4
#define C_IN 32
#define C_OUT 64
#define K_CHEB 6
#define M_POOL 12500
#define NT_ROWS (N_NODES + M_POOL)
#define NS32 ((size_t)N_NODES * C_IN)
#define ZH ((size_t)N_NODES * C_OUT)   // z elements per batch (fp16)
#define NWELEM (K_CHEB * 4 * 64 * 8)   // packed W elements

typedef _Float16 f16x8 __attribute__((ext_vector_type(8)));
typedef float f32x4 __attribute__((ext_vector_type(4)));
typedef unsigned short ushort_t;

__device__ __forceinline__ unsigned short f2h(float f) {
    union { _Float16 h; unsigned short u; } v;
    v.h = (_Float16)f;
    return v.u;
}

__device__ __forceinline__ float h2f(unsigned short u) {
    union { unsigned short u; _Float16 h; } v;
    v.u = u;
    return (float)v.h;
}

__device__ __forceinline__ __half2 u2h2(unsigned u) { return __builtin_bit_cast(__half2, u); }
__device__ __forceinline__ unsigned h22u(__half2 h) { return __builtin_bit_cast(unsigned, h); }

// ---------------- Fused independent prep: zero deg + W pack + x cast ----------------
__global__ void zero_pack_cast_kernel(int* __restrict__ deg,
                                      const float* __restrict__ W, ushort_t* __restrict__ Wp,
                                      const float* __restrict__ xin,
                                      unsigned int* __restrict__ xout, int n2) {
    int i = blockIdx.x * 256 + threadIdx.x;
    if (i < NT_ROWS) deg[i] = 0;
    if (i < NWELEM) {
        int j = i & 7;
        int lane = (i >> 3) & 63;
        int t = (i >> 9) & 3;
        int s = i >> 11;
        int k = (lane >> 4) * 8 + j;
        int colw = t * 16 + (lane & 15);
        Wp[i] = f2h(W[((size_t)s * C_IN + k) * C_OUT + colw]);
    }
    if (i < n2) {
        unsigned a = f2h(xin[2 * i]), b = f2h(xin[2 * i + 1]);
        xout[i] = a | (b << 16);
    }
}

// ---------------- deg/slot atomics ----------------
__global__ void deg_slot_kernel(const int* __restrict__ row, const int* __restrict__ prow,
                                int* __restrict__ deg, int* __restrict__ slot, int E, int P) {
    int e = blockIdx.x * blockDim.x + threadIdx.x;
    if (e < E) slot[e] = atomicAdd(&deg[row[e]], 1);
    else if (e < E + P) slot[e] = atomicAdd(&deg[N_NODES + prow[e - E]], 1);
}

// fused: dis + padded degree + per-block sum of padded degrees
__global__ void disdegp_bsum_kernel(const int* __restrict__ deg, float* __restrict__ dis,
                                    int* __restrict__ degp, int* __restrict__ bsum) {
    __shared__ int sm[256];
    int i = blockIdx.x * 256 + threadIdx.x;
    int dp = 0;
    if (i < N_NODES) {
        int d = deg[i];
        dis[i] = d > 0 ? rsqrtf((float)d) : 0.f;
        dp = (d + 7) & ~7;
        degp[i] = dp;
    } else if (i < NT_ROWS) {
        dp = deg[i];
        degp[i] = dp;
    }
    sm[threadIdx.x] = dp;
    __syncthreads();
    for (int s = 128; s > 0; s >>= 1) {
        if (threadIdx.x < s) sm[threadIdx.x] += sm[threadIdx.x + s];
        __syncthreads();
    }
    if (threadIdx.x == 0) bsum[blockIdx.x] = sm[0];
}

// rowptr: in-block scan of degp + self-computed prefix over bsum
__global__ void rowptr_kernel(const int* __restrict__ degp, const int* __restrict__ bsum,
                              int* __restrict__ rowptr, int N, int nb) {
    __shared__ int sm[256];
    __shared__ int sp[256];
    int bid = blockIdx.x;
    int i = bid * 256 + threadIdx.x;
    int t = threadIdx.x;
    int v = (i < N) ? degp[i] : 0;
    sm[t] = v;
    sp[t] = (t < bid) ? bsum[t] : 0;
    __syncthreads();
    for (int off = 1; off < 256; off <<= 1) {
        int u = (t >= off) ? sm[t - off] : 0;
        __syncthreads();
        sm[t] += u;
        __syncthreads();
    }
    for (int s = 128; s > 0; s >>= 1) {
        if (t < s) sp[t] += sp[t + s];
        __syncthreads();
    }
    int base = sp[0];
    if (i < N) rowptr[i] = base + sm[t] - v;
    if (bid == nb - 1 && t == 255) rowptr[N] = base + sm[255];
}

// fused: placement + pad-slot zeroing. cn entry = col<<16 | fp16(norm or pval)
__global__ void place_pad_kernel(const int* __restrict__ row, const int* __restrict__ col,
                                 const int* __restrict__ prow, const int* __restrict__ pcol,
                                 const float* __restrict__ pval, const float* __restrict__ dis,
                                 const int* __restrict__ rowptr, const int* __restrict__ slot,
                                 const int* __restrict__ deg,
                                 unsigned* __restrict__ cn, int E, int P) {
    int e = blockIdx.x * blockDim.x + threadIdx.x;
    if (e < E) {
        int r = row[e], c = col[e];
        float nm = -dis[r] * dis[c];
        cn[rowptr[r] + slot[e]] = ((unsigned)c << 16) | f2h(nm);
    } else if (e < E + P) {
        int i = e - E;
        int r = N_NODES + prow[i];
        cn[rowptr[r] + slot[e]] = ((unsigned)pcol[i] << 16) | f2h(pval[i]);
    } else if (e < E + P + N_NODES) {
        int r = e - E - P;
        int p = rowptr[r] + deg[r];
        int p1 = rowptr[r + 1];
        for (; p < p1; ++p) cn[p] = 0u;
    }
}

// ---------------- Chebyshev propagation v21: no LDS — direct 32B cn vector loads -------
// Rows 8-padded and rowptr 8-aligned => each 8-edge chunk is 32 contiguous bytes:
// 2 x uint4 loads per chunk (4 lanes/row share the line). No staging, no barrier;
// waves fully independent. Block = 64 rows x ONE batch (bid&3 -> per-XCD slice).
__global__ void __launch_bounds__(256, 8)
prop_kernel(const ushort_t* __restrict__ hf, const ushort_t* __restrict__ p2f,
            ushort_t* __restrict__ outf,
            const int* __restrict__ rowptr, const unsigned* __restrict__ cn, float alpha) {
    int bid = blockIdx.x;
    int b = bid & 3;
    int grp = bid >> 2;            // [0, 782)
    int lr = threadIdx.x >> 2;     // 0..63
    int cs = threadIdx.x & 3;      // channel oct
    int r = grp * 64 + lr;
    if (r >= N_NODES) return;
    const char* hb = (const char*)hf + (size_t)b * NS32 * 2;
    unsigned coff = (unsigned)cs * 16u;
    int p0 = rowptr[r], p1 = rowptr[r + 1];   // multiples of 8
    const uint4* cn4 = (const uint4*)cn;
    __half2 a0 = __float2half2_rn(0.f), a1 = a0, a2 = a0, a3 = a0;

    for (int p = p0; p < p1; p += 8) {
        uint4 c0 = cn4[p >> 2];         // entries p..p+3
        uint4 c1 = cn4[(p >> 2) + 1];   // entries p+4..p+7
        unsigned ew[8] = {c0.x, c0.y, c0.z, c0.w, c1.x, c1.y, c1.z, c1.w};
        unsigned off[8];
        __half2 n[8];
#pragma unroll
        for (int i = 0; i < 8; i++) {
            off[i] = ((ew[i] >> 16) << 6) + coff;
            unsigned lo = ew[i] & 0xffffu;
            n[i] = u2h2(lo | (lo << 16));
        }
        uint4 v[8];
#pragma unroll
        for (int i = 0; i < 8; i++) v[i] = *(const uint4*)(hb + off[i]);
#pragma unroll
        for (int i = 0; i < 8; i++) {
            a0 = __hfma2(u2h2(v[i].x), n[i], a0);
            a1 = __hfma2(u2h2(v[i].y), n[i], a1);
            a2 = __hfma2(u2h2(v[i].z), n[i], a2);
            a3 = __hfma2(u2h2(v[i].w), n[i], a3);
        }
    }

    unsigned ooff = ((unsigned)r << 6) + coff;
    uint4 o;
    if (p2f) {
        __half2 al2 = __float2half2_rn(alpha);
        uint4 pv = *(const uint4*)((const char*)p2f + (size_t)b * NS32 * 2 + ooff);
        o.x = h22u(__hfma2(a0, al2, __hneg2(u2h2(pv.x))));
        o.y = h22u(__hfma2(a1, al2, __hneg2(u2h2(pv.y))));
        o.z = h22u(__hfma2(a2, al2, __hneg2(u2h2(pv.z))));
        o.w = h22u(__hfma2(a3, al2, __hneg2(u2h2(pv.w))));
    } else {
        o.x = h22u(a0); o.y = h22u(a1); o.z = h22u(a2); o.w = h22u(a3);
    }
    *(uint4*)((char*)outf + (size_t)b * NS32 * 2 + ooff) = o;
}

// ---------------- Single fused 6-source MFMA GEMM + bias + ELU -> fp16 z ----------------
__global__ void gemm_mfma_kernel(const ushort_t* __restrict__ T0, const ushort_t* __restrict__ T1,
                                 const ushort_t* __restrict__ T2, const ushort_t* __restrict__ T3,
                                 const ushort_t* __restrict__ T4, const ushort_t* __restrict__ T5,
                                 const ushort_t* __restrict__ Wp,
                                 const float* __restrict__ bias, ushort_t* __restrict__ z) {
    int lane = threadIdx.x & 63;
    int wave = (blockIdx.x << 2) + (threadIdx.x >> 6);
    int r0 = wave << 4;
    int ga = r0 + (lane & 15);
    int koff = (lane >> 4) * 8;
    const ushort_t* Ts[6] = {T0, T1, T2, T3, T4, T5};

    f16x8 afr[6];
#pragma unroll
    for (int s = 0; s < 6; s++)
        afr[s] = *(const f16x8*)(Ts[s] + (size_t)ga * C_IN + koff);

    int orow = r0 + ((lane >> 4) << 2);
#pragma unroll
    for (int t = 0; t < 4; t++) {
        f32x4 acc = {0.f, 0.f, 0.f, 0.f};
#pragma unroll
        for (int s = 0; s < 6; s++) {
            f16x8 bfr = *(const f16x8*)(Wp + ((s * 4 + t) * 64 + lane) * 8);
            acc = __builtin_amdgcn_mfma_f32_16x16x32_f16(afr[s], bfr, acc, 0, 0, 0);
        }
        int col = (t << 4) + (lane & 15);
        float bv = bias[col];
#pragma unroll
        for (int rg = 0; rg < 4; rg++) {
            float v = acc[rg] + bv;
            z[(size_t)(orow + rg) * C_OUT + col] = f2h(v > 0.f ? v : (expf(v) - 1.f));
        }
    }
}

// ---------------- Pool: CSR gather-reduce, one batch per block (z L2 affinity) ----------
__global__ void pool_csr_kernel(const ushort_t* __restrict__ z, const int* __restrict__ rowptr,
                                const unsigned* __restrict__ cn, float* __restrict__ out) {
    int bid = blockIdx.x;
    int b = bid & 3;
    int r = (bid >> 2) * 8 + (threadIdx.x >> 5);
    int c2 = threadIdx.x & 31;   // channels 2c2, 2c2+1
    if (r >= M_POOL) return;
    const char* zb = (const char*)z + (size_t)b * ZH * 2;
    unsigned coff = (unsigned)c2 << 2;
    float s0 = 0.f, s1 = 0.f;
    int p0 = rowptr[N_NODES + r], p1 = rowptr[N_NODES + r + 1];
    for (int p = p0; p < p1; ++p) {
        unsigned e = cn[p];
        float v = h2f((ushort_t)(e & 0xffffu));
        unsigned u = *(const unsigned*)(zb + (((e >> 16) << 7) + coff));
        s0 += h2f((ushort_t)u) * v;
        s1 += h2f((ushort_t)(u >> 16)) * v;
    }
    size_t idx = (size_t)b * M_POOL * C_OUT + (size_t)r * C_OUT + 2 * c2;
    *(float2*)&out[idx] = make_float2(s0, s1);
}

extern "C" void kernel_launch(void* const* d_in, const int* in_sizes, int n_in,
                              void* d_out, int out_size, void* d_ws, size_t ws_size,
                              hipStream_t stream) {
    const float* x    = (const float*)d_in[0];
    const int*   ei   = (const int*)d_in[1];
    const int*   prow = (const int*)d_in[2];
    const int*   pcol = (const int*)d_in[3];
    const float* pval = (const float*)d_in[4];
    const float* W    = (const float*)d_in[5];
    const float* bias = (const float*)d_in[6];
    const int E = in_sizes[1] / 2;
    const int P = in_sizes[2];
    const int* row = ei;
    const int* col = ei + E;
    const int EP_MAX = E + 7 * N_NODES + P;  // 8-padded CSR upper bound

    char* ws = (char*)d_ws;
    size_t o = 0;
    auto alloc = [&](size_t bytes) -> char* {
        char* p = ws + o;
        o += (bytes + 255) & ~(size_t)255;
        return p;
    };
    int nb = (NT_ROWS + 255) / 256;
    int*      deg    = (int*)alloc((size_t)NT_ROWS * 4);
    int*      degp   = (int*)alloc((size_t)NT_ROWS * 4);
    float*    dis    = (float*)alloc((size_t)N_NODES * 4);
    int*      rowptr = (int*)alloc((size_t)(NT_ROWS + 1) * 4);
    int*      slot   = (int*)alloc((size_t)(E + P) * 4);
    int*      bsum   = (int*)alloc((size_t)nb * 4);
    unsigned* cn     = (unsigned*)alloc((size_t)EP_MAX * 4);
    ushort_t* Wp     = (ushort_t*)alloc((size_t)NWELEM * 2);
    ushort_t* xh     = (ushort_t*)alloc((size_t)B_SZ * NS32 * 2);
    ushort_t* hA     = (ushort_t*)alloc((size_t)B_SZ * NS32 * 2);  // T1
    ushort_t* hB     = (ushort_t*)alloc((size_t)B_SZ * NS32 * 2);  // T2
    ushort_t* hC     = (ushort_t*)alloc((size_t)B_SZ * NS32 * 2);  // T3
    ushort_t* hD     = (ushort_t*)alloc((size_t)B_SZ * NS32 * 2);  // T4
    ushort_t* hE     = (ushort_t*)alloc((size_t)B_SZ * NS32 * 2);  // T5
    ushort_t* z      = (ushort_t*)alloc((size_t)B_SZ * ZH * 2);

    int n2 = (int)(B_SZ * NS32 / 2);

    // prep (independent): zero deg + W pack + x cast in one launch
    zero_pack_cast_kernel<<<(n2 + 255) / 256, 256, 0, stream>>>(deg, W, Wp, x,
                                                                (unsigned int*)xh, n2);
    // CSR build
    deg_slot_kernel<<<(E + P + 255) / 256, 256, 0, stream>>>(row, prow, deg, slot, E, P);
    disdegp_bsum_kernel<<<nb, 256, 0, stream>>>(deg, dis, degp, bsum);
    rowptr_kernel<<<nb, 256, 0, stream>>>(degp, bsum, rowptr, NT_ROWS, nb);
    place_pad_kernel<<<(E + P + N_NODES + 255) / 256, 256, 0, stream>>>(
        row, col, prow, pcol, pval, dis, rowptr, slot, deg, cn, E, P);

    int prop_blocks = ((N_NODES + 63) / 64) * B_SZ;  // 782 * 4 = 3128
    int gemm_blocks = (B_SZ * N_NODES) / 64;         // 3125

    // Chebyshev chain: T1..T5 all kept
    prop_kernel<<<prop_blocks, 256, 0, stream>>>(xh, nullptr, hA, rowptr, cn, 1.0f);
    prop_kernel<<<prop_blocks, 256, 0, stream>>>(hA, xh, hB, rowptr, cn, 2.0f);
    prop_kernel<<<prop_blocks, 256, 0, stream>>>(hB, hA, hC, rowptr, cn, 2.0f);
    prop_kernel<<<prop_blocks, 256, 0, stream>>>(hC, hB, hD, rowptr, cn, 2.0f);
    prop_kernel<<<prop_blocks, 256, 0, stream>>>(hD, hC, hE, rowptr, cn, 2.0f);
    // z = ELU([x,T1..T5] @ W + bias), single pass
    gemm_mfma_kernel<<<gemm_blocks, 256, 0, stream>>>(xh, hA, hB, hC, hD, hE, Wp, bias, z);
    // pool (one batch per block)
    pool_csr_kernel<<<((M_POOL + 7) / 8) * B_SZ, 256, 0, stream>>>(z, rowptr, cn,
                                                                   (float*)d_out);
}

// Round 22
// 238.202 us; speedup vs baseline: 1.0075x; 1.0075x over previous
//
#include <hip/hip_runtime.h>
#include <hip/hip_fp16.h>
#include <cstdint>

#define N_NODES 50000
#define B_SZ 4
#define C_IN 32
#define C_OUT 64
#define K_CHEB 6
#define M_POOL 12500
#define NT_ROWS (N_NODES + M_POOL)
#define NS32 ((size_t)N_NODES * C_IN)
#define ZH ((size_t)N_NODES * C_OUT)   // z elements per batch (fp16)
#define CN_CAP 4096                    // LDS-staged cn entries per block (4B each)
#define CN_PAD(i) ((i) + ((i) >> 3))   // +1 entry per 8: bases hit 9m mod 32 banks
#define PROP_ROWS 128                  // rows per prop block (512 threads, 4 lanes/row)
#define NWELEM (K_CHEB * 4 * 64 * 8)   // packed W elements

typedef _Float16 f16x8 __attribute__((ext_vector_type(8)));
typedef float f32x4 __attribute__((ext_vector_type(4)));
typedef unsigned short ushort_t;

__device__ __forceinline__ unsigned short f2h(float f) {
    union { _Float16 h; unsigned short u; } v;
    v.h = (_Float16)f;
    return v.u;
}

__device__ __forceinline__ float h2f(unsigned short u) {
    union { unsigned short u; _Float16 h; } v;
    v.u = u;
    return (float)v.h;
}

__device__ __forceinline__ __half2 u2h2(unsigned u) { return __builtin_bit_cast(__half2, u); }
__device__ __forceinline__ unsigned h22u(__half2 h) { return __builtin_bit_cast(unsigned, h); }

// ---------------- Fused independent prep: zero deg + W pack + x cast ----------------
__global__ void zero_pack_cast_kernel(int* __restrict__ deg,
                                      const float* __restrict__ W, ushort_t* __restrict__ Wp,
                                      const float* __restrict__ xin,
                                      unsigned int* __restrict__ xout, int n2) {
    int i = blockIdx.x * 256 + threadIdx.x;
    if (i < NT_ROWS) deg[i] = 0;
    if (i < NWELEM) {
        int j = i & 7;
        int lane = (i >> 3) & 63;
        int t = (i >> 9) & 3;
        int s = i >> 11;
        int k = (lane >> 4) * 8 + j;
        int colw = t * 16 + (lane & 15);
        Wp[i] = f2h(W[((size_t)s * C_IN + k) * C_OUT + colw]);
    }
    if (i < n2) {
        unsigned a = f2h(xin[2 * i]), b = f2h(xin[2 * i + 1]);
        xout[i] = a | (b << 16);
    }
}

// ---------------- deg/slot atomics ----------------
__global__ void deg_slot_kernel(const int* __restrict__ row, const int* __restrict__ prow,
                                int* __restrict__ deg, int* __restrict__ slot, int E, int P) {
    int e = blockIdx.x * blockDim.x + threadIdx.x;
    if (e < E) slot[e] = atomicAdd(&deg[row[e]], 1);
    else if (e < E + P) slot[e] = atomicAdd(&deg[N_NODES + prow[e - E]], 1);
}

// fused: dis + padded degree + per-block sum of padded degrees
__global__ void disdegp_bsum_kernel(const int* __restrict__ deg, float* __restrict__ dis,
                                    int* __restrict__ degp, int* __restrict__ bsum) {
    __shared__ int sm[256];
    int i = blockIdx.x * 256 + threadIdx.x;
    int dp = 0;
    if (i < N_NODES) {
        int d = deg[i];
        dis[i] = d > 0 ? rsqrtf((float)d) : 0.f;
        dp = (d + 7) & ~7;
        degp[i] = dp;
    } else if (i < NT_ROWS) {
        dp = deg[i];
        degp[i] = dp;
    }
    sm[threadIdx.x] = dp;
    __syncthreads();
    for (int s = 128; s > 0; s >>= 1) {
        if (threadIdx.x < s) sm[threadIdx.x] += sm[threadIdx.x + s];
        __syncthreads();
    }
    if (threadIdx.x == 0) bsum[blockIdx.x] = sm[0];
}

// rowptr: in-block scan of degp + self-computed prefix over bsum
__global__ void rowptr_kernel(const int* __restrict__ degp, const int* __restrict__ bsum,
                              int* __restrict__ rowptr, int N, int nb) {
    __shared__ int sm[256];
    __shared__ int sp[256];
    int bid = blockIdx.x;
    int i = bid * 256 + threadIdx.x;
    int t = threadIdx.x;
    int v = (i < N) ? degp[i] : 0;
    sm[t] = v;
    sp[t] = (t < bid) ? bsum[t] : 0;
    __syncthreads();
    for (int off = 1; off < 256; off <<= 1) {
        int u = (t >= off) ? sm[t - off] : 0;
        __syncthreads();
        sm[t] += u;
        __syncthreads();
    }
    for (int s = 128; s > 0; s >>= 1) {
        if (t < s) sp[t] += sp[t + s];
        __syncthreads();
    }
    int base = sp[0];
    if (i < N) rowptr[i] = base + sm[t] - v;
    if (bid == nb - 1 && t == 255) rowptr[N] = base + sm[255];
}

// fused: placement + pad-slot zeroing. cn entry = col<<16 | fp16(norm or pval)
__global__ void place_pad_kernel(const int* __restrict__ row, const int* __restrict__ col,
                                 const int* __restrict__ prow, const int* __restrict__ pcol,
                                 const float* __restrict__ pval, const float* __restrict__ dis,
                                 const int* __restrict__ rowptr, const int* __restrict__ slot,
                                 const int* __restrict__ deg,
                                 unsigned* __restrict__ cn, int E, int P) {
    int e = blockIdx.x * blockDim.x + threadIdx.x;
    if (e < E) {
        int r = row[e], c = col[e];
        float nm = -dis[r] * dis[c];
        cn[rowptr[r] + slot[e]] = ((unsigned)c << 16) | f2h(nm);
    } else if (e < E + P) {
        int i = e - E;
        int r = N_NODES + prow[i];
        cn[rowptr[r] + slot[e]] = ((unsigned)pcol[i] << 16) | f2h(pval[i]);
    } else if (e < E + P + N_NODES) {
        int r = e - E - P;
        int p = rowptr[r] + deg[r];
        int p1 = rowptr[r + 1];
        for (; p < p1; ++p) cn[p] = 0u;
    }
}

// ---------------- Chebyshev propagation v22: 4B cn in LDS + 8-deep, 128 rows/block ------
// Block = 128 rows x ONE batch (bid&3 -> per-XCD slice), 512 threads, 4 lanes/row.
__global__ void __launch_bounds__(512, 8)
prop_kernel(const ushort_t* __restrict__ hf, const ushort_t* __restrict__ p2f,
            ushort_t* __restrict__ outf,
            const int* __restrict__ rowptr, const unsigned* __restrict__ cn, float alpha) {
    __shared__ unsigned lcn[CN_CAP + (CN_CAP >> 3)];
    int bid = blockIdx.x;
    int b = bid & 3;
    int grp = bid >> 2;            // [0, 391)
    int r0 = grp * PROP_ROWS;
    int rend = r0 + PROP_ROWS > N_NODES ? N_NODES : r0 + PROP_ROWS;
    int pbase = rowptr[r0];
    int pend = rowptr[rend];
    int cnt = pend - pbase;
    bool use_lds = (cnt <= CN_CAP);
    if (use_lds) {
        for (int i = threadIdx.x; i < cnt; i += 512) lcn[CN_PAD(i)] = cn[pbase + i];
    }
    __syncthreads();

    int lr = threadIdx.x >> 2;     // 0..127
    int cs = threadIdx.x & 3;      // channel oct
    int r = r0 + lr;
    if (r >= N_NODES) return;
    const char* hb = (const char*)hf + (size_t)b * NS32 * 2;
    unsigned coff = (unsigned)cs * 16u;
    __half2 a0 = __float2half2_rn(0.f), a1 = a0, a2 = a0, a3 = a0;

    if (use_lds) {
        int p0 = rowptr[r] - pbase, p1 = rowptr[r + 1] - pbase;
        for (int p = p0; p < p1; p += 8) {
            int base = CN_PAD(p);   // p multiple of 8 -> constant pad shift per chunk
            unsigned off[8];
            __half2 n[8];
#pragma unroll
            for (int i = 0; i < 8; i++) {
                unsigned e = lcn[base + i];
                off[i] = ((e >> 16) << 6) + coff;
                unsigned lo = e & 0xffffu;
                n[i] = u2h2(lo | (lo << 16));
            }
            uint4 v[8];
#pragma unroll
            for (int i = 0; i < 8; i++) v[i] = *(const uint4*)(hb + off[i]);
#pragma unroll
            for (int i = 0; i < 8; i++) {
                a0 = __hfma2(u2h2(v[i].x), n[i], a0);
                a1 = __hfma2(u2h2(v[i].y), n[i], a1);
                a2 = __hfma2(u2h2(v[i].z), n[i], a2);
                a3 = __hfma2(u2h2(v[i].w), n[i], a3);
            }
        }
    } else {
        int p0 = rowptr[r], p1 = rowptr[r + 1];
        for (int p = p0; p < p1; p += 8) {
            unsigned off[8];
            __half2 n[8];
#pragma unroll
            for (int i = 0; i < 8; i++) {
                unsigned e = cn[p + i];
                off[i] = ((e >> 16) << 6) + coff;
                unsigned lo = e & 0xffffu;
                n[i] = u2h2(lo | (lo << 16));
            }
            uint4 v[8];
#pragma unroll
            for (int i = 0; i < 8; i++) v[i] = *(const uint4*)(hb + off[i]);
#pragma unroll
            for (int i = 0; i < 8; i++) {
                a0 = __hfma2(u2h2(v[i].x), n[i], a0);
                a1 = __hfma2(u2h2(v[i].y), n[i], a1);
                a2 = __hfma2(u2h2(v[i].z), n[i], a2);
                a3 = __hfma2(u2h2(v[i].w), n[i], a3);
            }
        }
    }

    unsigned ooff = ((unsigned)r << 6) + coff;
    uint4 o;
    if (p2f) {
        __half2 al2 = __float2half2_rn(alpha);
        uint4 pv = *(const uint4*)((const char*)p2f + (size_t)b * NS32 * 2 + ooff);
        o.x = h22u(__hfma2(a0, al2, __hneg2(u2h2(pv.x))));
        o.y = h22u(__hfma2(a1, al2, __hneg2(u2h2(pv.y))));
        o.z = h22u(__hfma2(a2, al2, __hneg2(u2h2(pv.z))));
        o.w = h22u(__hfma2(a3, al2, __hneg2(u2h2(pv.w))));
    } else {
        o.x = h22u(a0); o.y = h22u(a1); o.z = h22u(a2); o.w = h22u(a3);
    }
    *(uint4*)((char*)outf + (size_t)b * NS32 * 2 + ooff) = o;
}

// ---------------- Single fused 6-source MFMA GEMM + bias + ELU -> fp16 z ----------------
__global__ void gemm_mfma_kernel(const ushort_t* __restrict__ T0, const ushort_t* __restrict__ T1,
                                 const ushort_t* __restrict__ T2, const ushort_t* __restrict__ T3,
                                 const ushort_t* __restrict__ T4, const ushort_t* __restrict__ T5,
                                 const ushort_t* __restrict__ Wp,
                                 const float* __restrict__ bias, ushort_t* __restrict__ z) {
    int lane = threadIdx.x & 63;
    int wave = (blockIdx.x << 2) + (threadIdx.x >> 6);
    int r0 = wave << 4;
    int ga = r0 + (lane & 15);
    int koff = (lane >> 4) * 8;
    const ushort_t* Ts[6] = {T0, T1, T2, T3, T4, T5};

    f16x8 afr[6];
#pragma unroll
    for (int s = 0; s < 6; s++)
        afr[s] = *(const f16x8*)(Ts[s] + (size_t)ga * C_IN + koff);

    int orow = r0 + ((lane >> 4) << 2);
#pragma unroll
    for (int t = 0; t < 4; t++) {
        f32x4 acc = {0.f, 0.f, 0.f, 0.f};
#pragma unroll
        for (int s = 0; s < 6; s++) {
            f16x8 bfr = *(const f16x8*)(Wp + ((s * 4 + t) * 64 + lane) * 8);
            acc = __builtin_amdgcn_mfma_f32_16x16x32_f16(afr[s], bfr, acc, 0, 0, 0);
        }
        int col = (t << 4) + (lane & 15);
        float bv = bias[col];
#pragma unroll
        for (int rg = 0; rg < 4; rg++) {
            float v = acc[rg] + bv;
            z[(size_t)(orow + rg) * C_OUT + col] = f2h(v > 0.f ? v : (expf(v) - 1.f));
        }
    }
}

// ---------------- Pool: CSR gather-reduce, one batch per block (z L2 affinity) ----------
__global__ void pool_csr_kernel(const ushort_t* __restrict__ z, const int* __restrict__ rowptr,
                                const unsigned* __restrict__ cn, float* __restrict__ out) {
    int bid = blockIdx.x;
    int b = bid & 3;
    int r = (bid >> 2) * 8 + (threadIdx.x >> 5);
    int c2 = threadIdx.x & 31;   // channels 2c2, 2c2+1
    if (r >= M_POOL) return;
    const char* zb = (const char*)z + (size_t)b * ZH * 2;
    unsigned coff = (unsigned)c2 << 2;
    float s0 = 0.f, s1 = 0.f;
    int p0 = rowptr[N_NODES + r], p1 = rowptr[N_NODES + r + 1];
    for (int p = p0; p < p1; ++p) {
        unsigned e = cn[p];
        float v = h2f((ushort_t)(e & 0xffffu));
        unsigned u = *(const unsigned*)(zb + (((e >> 16) << 7) + coff));
        s0 += h2f((ushort_t)u) * v;
        s1 += h2f((ushort_t)(u >> 16)) * v;
    }
    size_t idx = (size_t)b * M_POOL * C_OUT + (size_t)r * C_OUT + 2 * c2;
    *(float2*)&out[idx] = make_float2(s0, s1);
}

extern "C" void kernel_launch(void* const* d_in, const int* in_sizes, int n_in,
                              void* d_out, int out_size, void* d_ws, size_t ws_size,
                              hipStream_t stream) {
    const float* x    = (const float*)d_in[0];
    const int*   ei   = (const int*)d_in[1];
    const int*   prow = (const int*)d_in[2];
    const int*   pcol = (const int*)d_in[3];
    const float* pval = (const float*)d_in[4];
    const float* W    = (const float*)d_in[5];
    const float* bias = (const float*)d_in[6];
    const int E = in_sizes[1] / 2;
    const int P = in_sizes[2];
    const int* row = ei;
    const int* col = ei + E;
    const int EP_MAX = E + 7 * N_NODES + P;  // 8-padded CSR upper bound

    char* ws = (char*)d_ws;
    size_t o = 0;
    auto alloc = [&](size_t bytes) -> char* {
        char* p = ws + o;
        o += (bytes + 255) & ~(size_t)255;
        return p;
    };
    int nb = (NT_ROWS + 255) / 256;
    int*      deg    = (int*)alloc((size_t)NT_ROWS * 4);
    int*      degp   = (int*)alloc((size_t)NT_ROWS * 4);
    float*    dis    = (float*)alloc((size_t)N_NODES * 4);
    int*      rowptr = (int*)alloc((size_t)(NT_ROWS + 1) * 4);
    int*      slot   = (int*)alloc((size_t)(E + P) * 4);
    int*      bsum   = (int*)alloc((size_t)nb * 4);
    unsigned* cn     = (unsigned*)alloc((size_t)EP_MAX * 4);
    ushort_t* Wp     = (ushort_t*)alloc((size_t)NWELEM * 2);
    ushort_t* xh     = (ushort_t*)alloc((size_t)B_SZ * NS32 * 2);
    ushort_t* hA     = (ushort_t*)alloc((size_t)B_SZ * NS32 * 2);  // T1
    ushort_t* hB     = (ushort_t*)alloc((size_t)B_SZ * NS32 * 2);  // T2
    ushort_t* hC     = (ushort_t*)alloc((size_t)B_SZ * NS32 * 2);  // T3
    ushort_t* hD     = (ushort_t*)alloc((size_t)B_SZ * NS32 * 2);  // T4
    ushort_t* hE     = (ushort_t*)alloc((size_t)B_SZ * NS32 * 2);  // T5
    ushort_t* z      = (ushort_t*)alloc((size_t)B_SZ * ZH * 2);

    int n2 = (int)(B_SZ * NS32 / 2);

    // prep (independent): zero deg + W pack + x cast in one launch
    zero_pack_cast_kernel<<<(n2 + 255) / 256, 256, 0, stream>>>(deg, W, Wp, x,
                                                                (unsigned int*)xh, n2);
    // CSR build
    deg_slot_kernel<<<(E + P + 255) / 256, 256, 0, stream>>>(row, prow, deg, slot, E, P);
    disdegp_bsum_kernel<<<nb, 256, 0, stream>>>(deg, dis, degp, bsum);
    rowptr_kernel<<<nb, 256, 0, stream>>>(degp, bsum, rowptr, NT_ROWS, nb);
    place_pad_kernel<<<(E + P + N_NODES + 255) / 256, 256, 0, stream>>>(
        row, col, prow, pcol, pval, dis, rowptr, slot, deg, cn, E, P);

    int prop_blocks = ((N_NODES + PROP_ROWS - 1) / PROP_ROWS) * B_SZ;  // 391 * 4 = 1564
    int gemm_blocks = (B_SZ * N_NODES) / 64;                            // 3125

    // Chebyshev chain: T1..T5 all kept
    prop_kernel<<<prop_blocks, 512, 0, stream>>>(xh, nullptr, hA, rowptr, cn, 1.0f);
    prop_kernel<<<prop_blocks, 512, 0, stream>>>(hA, xh, hB, rowptr, cn, 2.0f);
    prop_kernel<<<prop_blocks, 512, 0, stream>>>(hB, hA, hC, rowptr, cn, 2.0f);
    prop_kernel<<<prop_blocks, 512, 0, stream>>>(hC, hB, hD, rowptr, cn, 2.0f);
    prop_kernel<<<prop_blocks, 512, 0, stream>>>(hD, hC, hE, rowptr, cn, 2.0f);
    // z = ELU([x,T1..T5] @ W + bias), single pass
    gemm_mfma_kernel<<<gemm_blocks, 256, 0, stream>>>(xh, hA, hB, hC, hD, hE, Wp, bias, z);
    // pool (one batch per block)
    pool_csr_kernel<<<((M_POOL + 7) / 8) * B_SZ, 256, 0, stream>>>(z, rowptr, cn,
                                                                   (float*)d_out);
}

// Round 23
// 231.083 us; speedup vs baseline: 1.0385x; 1.0308x over previous
//
#include <hip/hip_runtime.h>
#include <hip/hip_fp16.h>
#include <cstdint>

#define N_NODES 50000
#define B_SZ 4
#define C_IN 32
#define C_OUT 64
#define K_CHEB 6
#define M_POOL 12500
#define NT_ROWS (N_NODES + M_POOL)
#define NS32 ((size_t)N_NODES * C_IN)
#define ZH ((size_t)N_NODES * C_OUT)   // z elements per batch (fp16)
#define CN_CAP 2048                    // LDS-staged cn entries per block (4B each)
#define CN_PAD(i) ((i) + ((i) >> 3))   // +1 entry per 8: bases hit 9m mod 32 banks
#define NWELEM (K_CHEB * 4 * 64 * 8)   // packed W elements

typedef _Float16 f16x8 __attribute__((ext_vector_type(8)));
typedef float f32x4 __attribute__((ext_vector_type(4)));
typedef unsigned short ushort_t;

__device__ __forceinline__ unsigned short f2h(float f) {
    union { _Float16 h; unsigned short u; } v;
    v.h = (_Float16)f;
    return v.u;
}

__device__ __forceinline__ float h2f(unsigned short u) {
    union { unsigned short u; _Float16 h; } v;
    v.u = u;
    return (float)v.h;
}

__device__ __forceinline__ __half2 u2h2(unsigned u) { return __builtin_bit_cast(__half2, u); }
__device__ __forceinline__ unsigned h22u(__half2 h) { return __builtin_bit_cast(unsigned, h); }

// ---------------- Fused independent prep: zero deg + W pack + x cast ----------------
__global__ void zero_pack_cast_kernel(int* __restrict__ deg,
                                      const float* __restrict__ W, ushort_t* __restrict__ Wp,
                                      const float* __restrict__ xin,
                                      unsigned int* __restrict__ xout, int n2) {
    int i = blockIdx.x * 256 + threadIdx.x;
    if (i < NT_ROWS) deg[i] = 0;
    if (i < NWELEM) {
        int j = i & 7;
        int lane = (i >> 3) & 63;
        int t = (i >> 9) & 3;
        int s = i >> 11;
        int k = (lane >> 4) * 8 + j;
        int colw = t * 16 + (lane & 15);
        Wp[i] = f2h(W[((size_t)s * C_IN + k) * C_OUT + colw]);
    }
    if (i < n2) {
        unsigned a = f2h(xin[2 * i]), b = f2h(xin[2 * i + 1]);
        xout[i] = a | (b << 16);
    }
}

// ---------------- deg/slot atomics ----------------
__global__ void deg_slot_kernel(const int* __restrict__ row, const int* __restrict__ prow,
                                int* __restrict__ deg, int* __restrict__ slot, int E, int P) {
    int e = blockIdx.x * blockDim.x + threadIdx.x;
    if (e < E) slot[e] = atomicAdd(&deg[row[e]], 1);
    else if (e < E + P) slot[e] = atomicAdd(&deg[N_NODES + prow[e - E]], 1);
}

// fused: dis + padded degree + per-block sum of padded degrees
__global__ void disdegp_bsum_kernel(const int* __restrict__ deg, float* __restrict__ dis,
                                    int* __restrict__ degp, int* __restrict__ bsum) {
    __shared__ int sm[256];
    int i = blockIdx.x * 256 + threadIdx.x;
    int dp = 0;
    if (i < N_NODES) {
        int d = deg[i];
        dis[i] = d > 0 ? rsqrtf((float)d) : 0.f;
        dp = (d + 7) & ~7;
        degp[i] = dp;
    } else if (i < NT_ROWS) {
        dp = deg[i];
        degp[i] = dp;
    }
    sm[threadIdx.x] = dp;
    __syncthreads();
    for (int s = 128; s > 0; s >>= 1) {
        if (threadIdx.x < s) sm[threadIdx.x] += sm[threadIdx.x + s];
        __syncthreads();
    }
    if (threadIdx.x == 0) bsum[blockIdx.x] = sm[0];
}

// rowptr: in-block scan of degp + self-computed prefix over bsum (no separate scan launch)
__global__ void rowptr_kernel(const int* __restrict__ degp, const int* __restrict__ bsum,
                              int* __restrict__ rowptr, int N, int nb) {
    __shared__ int sm[256];
    __shared__ int sp[256];
    int bid = blockIdx.x;
    int i = bid * 256 + threadIdx.x;
    int t = threadIdx.x;
    int v = (i < N) ? degp[i] : 0;
    sm[t] = v;
    sp[t] = (t < bid) ? bsum[t] : 0;   // prefix source over earlier blocks
    __syncthreads();
    // inclusive scan of sm
    for (int off = 1; off < 256; off <<= 1) {
        int u = (t >= off) ? sm[t - off] : 0;
        __syncthreads();
        sm[t] += u;
        __syncthreads();
    }
    // reduce sp -> base
    for (int s = 128; s > 0; s >>= 1) {
        if (t < s) sp[t] += sp[t + s];
        __syncthreads();
    }
    int base = sp[0];
    if (i < N) rowptr[i] = base + sm[t] - v;  // exclusive prefix
    if (bid == nb - 1 && t == 255) rowptr[N] = base + sm[255];
}

// fused: placement (threads [0, E+P)) + pad-slot zeroing (threads [E+P, E+P+N)).
// cn entry = col<<16 | fp16(norm or pval)  (4 bytes per edge)
__global__ void place_pad_kernel(const int* __restrict__ row, const int* __restrict__ col,
                                 const int* __restrict__ prow, const int* __restrict__ pcol,
                                 const float* __restrict__ pval, const float* __restrict__ dis,
                                 const int* __restrict__ rowptr, const int* __restrict__ slot,
                                 const int* __restrict__ deg,
                                 unsigned* __restrict__ cn, int E, int P) {
    int e = blockIdx.x * blockDim.x + threadIdx.x;
    if (e < E) {
        int r = row[e], c = col[e];
        float nm = -dis[r] * dis[c];
        cn[rowptr[r] + slot[e]] = ((unsigned)c << 16) | f2h(nm);
    } else if (e < E + P) {
        int i = e - E;
        int r = N_NODES + prow[i];
        cn[rowptr[r] + slot[e]] = ((unsigned)pcol[i] << 16) | f2h(pval[i]);
    } else if (e < E + P + N_NODES) {
        int r = e - E - P;
        int p = rowptr[r] + deg[r];
        int p1 = rowptr[r + 1];
        for (; p < p1; ++p) cn[p] = 0u;
    }
}

// ---------------- Chebyshev propagation v20: 4B cn + anti-conflict LDS + 8-deep -------
__global__ void __launch_bounds__(256, 8)
prop_kernel(const ushort_t* __restrict__ hf, const ushort_t* __restrict__ p2f,
            ushort_t* __restrict__ outf,
            const int* __restrict__ rowptr, const unsigned* __restrict__ cn, float alpha) {
    __shared__ unsigned lcn[CN_CAP + (CN_CAP >> 3)];
    int bid = blockIdx.x;
    int b = bid & 3;
    int grp = bid >> 2;            // [0, 782)
    int r0 = grp * 64;
    int rend = r0 + 64 > N_NODES ? N_NODES : r0 + 64;
    int pbase = rowptr[r0];
    int pend = rowptr[rend];
    int cnt = pend - pbase;
    bool use_lds = (cnt <= CN_CAP);
    if (use_lds) {
        for (int i = threadIdx.x; i < cnt; i += 256) lcn[CN_PAD(i)] = cn[pbase + i];
    }
    __syncthreads();

    int lr = threadIdx.x >> 2;     // 0..63
    int cs = threadIdx.x & 3;      // channel oct
    int r = r0 + lr;
    if (r >= N_NODES) return;
    const char* hb = (const char*)hf + (size_t)b * NS32 * 2;
    unsigned coff = (unsigned)cs * 16u;
    __half2 a0 = __float2half2_rn(0.f), a1 = a0, a2 = a0, a3 = a0;

    if (use_lds) {
        int p0 = rowptr[r] - pbase, p1 = rowptr[r + 1] - pbase;
        for (int p = p0; p < p1; p += 8) {
            int base = CN_PAD(p);   // p multiple of 8 -> constant pad shift per chunk
            unsigned off[8];
            __half2 n[8];
#pragma unroll
            for (int i = 0; i < 8; i++) {
                unsigned e = lcn[base + i];
                off[i] = ((e >> 16) << 6) + coff;
                unsigned lo = e & 0xffffu;
                n[i] = u2h2(lo | (lo << 16));
            }
            uint4 v[8];
#pragma unroll
            for (int i = 0; i < 8; i++) v[i] = *(const uint4*)(hb + off[i]);
#pragma unroll
            for (int i = 0; i < 8; i++) {
                a0 = __hfma2(u2h2(v[i].x), n[i], a0);
                a1 = __hfma2(u2h2(v[i].y), n[i], a1);
                a2 = __hfma2(u2h2(v[i].z), n[i], a2);
                a3 = __hfma2(u2h2(v[i].w), n[i], a3);
            }
        }
    } else {
        int p0 = rowptr[r], p1 = rowptr[r + 1];
        for (int p = p0; p < p1; p += 8) {
            unsigned off[8];
            __half2 n[8];
#pragma unroll
            for (int i = 0; i < 8; i++) {
                unsigned e = cn[p + i];
                off[i] = ((e >> 16) << 6) + coff;
                unsigned lo = e & 0xffffu;
                n[i] = u2h2(lo | (lo << 16));
            }
            uint4 v[8];
#pragma unroll
            for (int i = 0; i < 8; i++) v[i] = *(const uint4*)(hb + off[i]);
#pragma unroll
            for (int i = 0; i < 8; i++) {
                a0 = __hfma2(u2h2(v[i].x), n[i], a0);
                a1 = __hfma2(u2h2(v[i].y), n[i], a1);
                a2 = __hfma2(u2h2(v[i].z), n[i], a2);
                a3 = __hfma2(u2h2(v[i].w), n[i], a3);
            }
        }
    }

    unsigned ooff = ((unsigned)r << 6) + coff;
    uint4 o;
    if (p2f) {
        __half2 al2 = __float2half2_rn(alpha);
        uint4 pv = *(const uint4*)((const char*)p2f + (size_t)b * NS32 * 2 + ooff);
        o.x = h22u(__hfma2(a0, al2, __hneg2(u2h2(pv.x))));
        o.y = h22u(__hfma2(a1, al2, __hneg2(u2h2(pv.y))));
        o.z = h22u(__hfma2(a2, al2, __hneg2(u2h2(pv.z))));
        o.w = h22u(__hfma2(a3, al2, __hneg2(u2h2(pv.w))));
    } else {
        o.x = h22u(a0); o.y = h22u(a1); o.z = h22u(a2); o.w = h22u(a3);
    }
    *(uint4*)((char*)outf + (size_t)b * NS32 * 2 + ooff) = o;
}

// ---------------- Single fused 6-source MFMA GEMM + bias + ELU -> fp16 z ----------------
__global__ void gemm_mfma_kernel(const ushort_t* __restrict__ T0, const ushort_t* __restrict__ T1,
                                 const ushort_t* __restrict__ T2, const ushort_t* __restrict__ T3,
                                 const ushort_t* __restrict__ T4, const ushort_t* __restrict__ T5,
                                 const ushort_t* __restrict__ Wp,
                                 const float* __restrict__ bias, ushort_t* __restrict__ z) {
    int lane = threadIdx.x & 63;
    int wave = (blockIdx.x << 2) + (threadIdx.x >> 6);
    int r0 = wave << 4;
    int ga = r0 + (lane & 15);
    int koff = (lane >> 4) * 8;
    const ushort_t* Ts[6] = {T0, T1, T2, T3, T4, T5};

    f16x8 afr[6];
#pragma unroll
    for (int s = 0; s < 6; s++)
        afr[s] = *(const f16x8*)(Ts[s] + (size_t)ga * C_IN + koff);

    int orow = r0 + ((lane >> 4) << 2);
#pragma unroll
    for (int t = 0; t < 4; t++) {
        f32x4 acc = {0.f, 0.f, 0.f, 0.f};
#pragma unroll
        for (int s = 0; s < 6; s++) {
            f16x8 bfr = *(const f16x8*)(Wp + ((s * 4 + t) * 64 + lane) * 8);
            acc = __builtin_amdgcn_mfma_f32_16x16x32_f16(afr[s], bfr, acc, 0, 0, 0);
        }
        int col = (t << 4) + (lane & 15);
        float bv = bias[col];
#pragma unroll
        for (int rg = 0; rg < 4; rg++) {
            float v = acc[rg] + bv;
            z[(size_t)(orow + rg) * C_OUT + col] = f2h(v > 0.f ? v : (expf(v) - 1.f));
        }
    }
}

// ---------------- Pool: CSR gather-reduce, one batch per block (z L2 affinity) ----------
__global__ void pool_csr_kernel(const ushort_t* __restrict__ z, const int* __restrict__ rowptr,
                                const unsigned* __restrict__ cn, float* __restrict__ out) {
    int bid = blockIdx.x;
    int b = bid & 3;
    int r = (bid >> 2) * 8 + (threadIdx.x >> 5);
    int c2 = threadIdx.x & 31;   // channels 2c2, 2c2+1
    if (r >= M_POOL) return;
    const char* zb = (const char*)z + (size_t)b * ZH * 2;
    unsigned coff = (unsigned)c2 << 2;
    float s0 = 0.f, s1 = 0.f;
    int p0 = rowptr[N_NODES + r], p1 = rowptr[N_NODES + r + 1];
    for (int p = p0; p < p1; ++p) {
        unsigned e = cn[p];
        float v = h2f((ushort_t)(e & 0xffffu));
        unsigned u = *(const unsigned*)(zb + (((e >> 16) << 7) + coff));
        s0 += h2f((ushort_t)u) * v;
        s1 += h2f((ushort_t)(u >> 16)) * v;
    }
    size_t idx = (size_t)b * M_POOL * C_OUT + (size_t)r * C_OUT + 2 * c2;
    *(float2*)&out[idx] = make_float2(s0, s1);
}

extern "C" void kernel_launch(void* const* d_in, const int* in_sizes, int n_in,
                              void* d_out, int out_size, void* d_ws, size_t ws_size,
                              hipStream_t stream) {
    const float* x    = (const float*)d_in[0];
    const int*   ei   = (const int*)d_in[1];
    const int*   prow = (const int*)d_in[2];
    const int*   pcol = (const int*)d_in[3];
    const float* pval = (const float*)d_in[4];
    const float* W    = (const float*)d_in[5];
    const float* bias = (const float*)d_in[6];
    const int E = in_sizes[1] / 2;
    const int P = in_sizes[2];
    const int* row = ei;
    const int* col = ei + E;
    const int EP_MAX = E + 7 * N_NODES + P;  // 8-padded CSR upper bound

    char* ws = (char*)d_ws;
    size_t o = 0;
    auto alloc = [&](size_t bytes) -> char* {
        char* p = ws + o;
        o += (bytes + 255) & ~(size_t)255;
        return p;
    };
    int nb = (NT_ROWS + 255) / 256;
    int*      deg    = (int*)alloc((size_t)NT_ROWS * 4);
    int*      degp   = (int*)alloc((size_t)NT_ROWS * 4);
    float*    dis    = (float*)alloc((size_t)N_NODES * 4);
    int*      rowptr = (int*)alloc((size_t)(NT_ROWS + 1) * 4);
    int*      slot   = (int*)alloc((size_t)(E + P) * 4);
    int*      bsum   = (int*)alloc((size_t)nb * 4);
    unsigned* cn     = (unsigned*)alloc((size_t)EP_MAX * 4);
    ushort_t* Wp     = (ushort_t*)alloc((size_t)NWELEM * 2);
    ushort_t* xh     = (ushort_t*)alloc((size_t)B_SZ * NS32 * 2);
    ushort_t* hA     = (ushort_t*)alloc((size_t)B_SZ * NS32 * 2);  // T1
    ushort_t* hB     = (ushort_t*)alloc((size_t)B_SZ * NS32 * 2);  // T2
    ushort_t* hC     = (ushort_t*)alloc((size_t)B_SZ * NS32 * 2);  // T3
    ushort_t* hD     = (ushort_t*)alloc((size_t)B_SZ * NS32 * 2);  // T4
    ushort_t* hE     = (ushort_t*)alloc((size_t)B_SZ * NS32 * 2);  // T5
    ushort_t* z      = (ushort_t*)alloc((size_t)B_SZ * ZH * 2);

    int n2 = (int)(B_SZ * NS32 / 2);

    // prep (independent): zero deg + W pack + x cast in one launch
    zero_pack_cast_kernel<<<(n2 + 255) / 256, 256, 0, stream>>>(deg, W, Wp, x,
                                                                (unsigned int*)xh, n2);
    // CSR build
    deg_slot_kernel<<<(E + P + 255) / 256, 256, 0, stream>>>(row, prow, deg, slot, E, P);
    disdegp_bsum_kernel<<<nb, 256, 0, stream>>>(deg, dis, degp, bsum);
    rowptr_kernel<<<nb, 256, 0, stream>>>(degp, bsum, rowptr, NT_ROWS, nb);
    place_pad_kernel<<<(E + P + N_NODES + 255) / 256, 256, 0, stream>>>(
        row, col, prow, pcol, pval, dis, rowptr, slot, deg, cn, E, P);

    int prop_blocks = ((N_NODES + 63) / 64) * B_SZ;  // 782 * 4 = 3128
    int gemm_blocks = (B_SZ * N_NODES) / 64;         // 3125

    // Chebyshev chain: T1..T5 all kept
    prop_kernel<<<prop_blocks, 256, 0, stream>>>(xh, nullptr, hA, rowptr, cn, 1.0f);
    prop_kernel<<<prop_blocks, 256, 0, stream>>>(hA, xh, hB, rowptr, cn, 2.0f);
    prop_kernel<<<prop_blocks, 256, 0, stream>>>(hB, hA, hC, rowptr, cn, 2.0f);
    prop_kernel<<<prop_blocks, 256, 0, stream>>>(hC, hB, hD, rowptr, cn, 2.0f);
    prop_kernel<<<prop_blocks, 256, 0, stream>>>(hD, hC, hE, rowptr, cn, 2.0f);
    // z = ELU([x,T1..T5] @ W + bias), single pass
    gemm_mfma_kernel<<<gemm_blocks, 256, 0, stream>>>(xh, hA, hB, hC, hD, hE, Wp, bias, z);
    // pool (one batch per block)
    pool_csr_kernel<<<((M_POOL + 7) / 8) * B_SZ, 256, 0, stream>>>(z, rowptr, cn,
                                                                   (float*)d_out);
}